// Round 5
// baseline (143.068 us; speedup 1.0000x reference)
//
#include <hip/hip_runtime.h>
#include <math.h>

// Problem constants
#define Bb   8
#define Dd   256
#define Tt   500
#define SPK  2000
#define SPKP 2048     // padded speakers
#define BN   16       // B*N
#define L2E  1.4426950408889634f
#define LN2  0.6931471805599453f

// fast hw transcendentals: v_exp_f32 = 2^x, v_log_f32 = log2(x)
#define EXP2F(x) __builtin_amdgcn_exp2f(x)
#define LOG2F(x) __builtin_amdgcn_logf(x)

// ---- ws layout (float indices) ----
#define F_ESN   0                      // -alpha*||E_s||^2 * log2(e), pad rows = -1e30   [2048]
#define F_DMINP 2048                   // per-block dmin partial sums          [64]
#define F_PM    4096                   // partial m (log2 domain) [16*512*4]
#define F_PL    (F_PM + 32768)         // partial l (log2 domain) [16*512*4]
#define EBF_FLOATS (F_PL + 32768)      // = 69632
#define EBF_BYTES ((size_t)EBF_FLOATS * 4)

typedef __bf16 v8bf __attribute__((ext_vector_type(8)));
typedef float  v4f  __attribute__((ext_vector_type(4)));

__device__ inline unsigned pack_bf16x2(float lo, float hi) {
    union { __bf16 h; unsigned short u; } a, b;
    a.h = (__bf16)lo; b.h = (__bf16)hi;
    return ((unsigned)b.u << 16) | (unsigned)a.u;
}

// ================= kernel 1: prep_all =================
// blocks 0..511   : E -> bf16 (4 rows/block) + esn2 (log2-scaled)
// blocks 512..527 : gather out[0..4095]
// blocks 528..591 : dmin partials
__global__ __launch_bounds__(256) void prep_all_kernel(
        const float* __restrict__ E, const int* __restrict__ S,
        const float* __restrict__ H, const float* __restrict__ alpha,
        const float* __restrict__ beta, float* __restrict__ ws,
        float* __restrict__ out) {
    int bid = blockIdx.x;
    int tid = threadIdx.x;

    if (bid < 512) {
        int s = bid * 4 + (tid >> 6);     // 0..2047
        int lane = tid & 63;
        float4 v = make_float4(0.f, 0.f, 0.f, 0.f);
        if (s < SPK) v = ((const float4*)E)[s * 64 + lane];
        __bf16* ebf = (__bf16*)((char*)ws + EBF_BYTES);
        uint2 pp;
        pp.x = pack_bf16x2(v.x, v.y);
        pp.y = pack_bf16x2(v.z, v.w);
        *(uint2*)(ebf + (size_t)s * Dd + lane * 4) = pp;
        float acc = v.x * v.x + v.y * v.y + v.z * v.z + v.w * v.w;
        #pragma unroll
        for (int off = 32; off > 0; off >>= 1) acc += __shfl_down(acc, off, 64);
        if (lane == 0) ws[F_ESN + s] = (s < SPK) ? (-alpha[0] * acc * L2E) : -1e30f;
    } else if (bid < 528) {
        int i = (bid - 512) * 256 + tid;  // 0..4095
        int bn = i >> 8, d = i & 255;
        out[i] = E[(size_t)S[bn * Tt] * Dd + d];
    } else {
        __shared__ float4 shm[4][64];
        int q = bid - 528;                // 0..63
        int b = q >> 3;
        int t0 = (q & 7) * 64;
        int tl = tid & 63;
        int wv = tid >> 6;
        int t = t0 + tl;
        bool ok = (t < Tt);
        int tc = ok ? t : (Tt - 1);
        int s0 = S[(b * 2 + 0) * Tt + tc];
        int s1 = S[(b * 2 + 1) * Tt + tc];
        const float* h0 = H + ((size_t)(b * 2 + 0) * Dd) * Tt + tc;
        const float* h1 = H + ((size_t)(b * 2 + 1) * Dd) * Tt + tc;
        const float* e0 = E + (size_t)s0 * Dd;
        const float* e1 = E + (size_t)s1 * Dd;
        float d00 = 0, d01 = 0, d10 = 0, d11 = 0;
        int dbase = wv * 64;
        #pragma unroll 4
        for (int dd = 0; dd < 64; ++dd) {
            int d = dbase + dd;
            float x0 = h0[(size_t)d * Tt], x1 = h1[(size_t)d * Tt];
            float y0 = e0[d], y1 = e1[d];
            float u;
            u = x0 - y0; d00 = fmaf(u, u, d00);
            u = x0 - y1; d01 = fmaf(u, u, d01);
            u = x1 - y0; d10 = fmaf(u, u, d10);
            u = x1 - y1; d11 = fmaf(u, u, d11);
        }
        shm[wv][tl] = make_float4(d00, d01, d10, d11);
        __syncthreads();
        if (wv == 0) {
            float4 p0 = shm[0][tl], p1 = shm[1][tl], p2 = shm[2][tl], p3 = shm[3][tl];
            d00 = p0.x + p1.x + p2.x + p3.x;
            d01 = p0.y + p1.y + p2.y + p3.y;
            d10 = p0.z + p1.z + p2.z + p3.z;
            d11 = p0.w + p1.w + p2.w + p3.w;
            float dm = fminf(d00 + d11, d01 + d10);
            float val = ok ? (-alpha[0] * dm + beta[0]) : 0.f;
            #pragma unroll
            for (int off = 32; off > 0; off >>= 1) val += __shfl_down(val, off, 64);
            if (tl == 0) ws[F_DMINP + q] = val;
        }
    }
}

// ================= kernel 2: MFMA lse (log2 domain) =================
// grid (bn=16, ttile=16 [32 t], schunk=4 [512 spk]), 256 threads = 4 waves (speaker-split)
__global__ __launch_bounds__(256, 2) void lse_mfma_kernel(
        const float* __restrict__ H, const float* __restrict__ alpha,
        const float* __restrict__ beta, float* __restrict__ ws) {
    __shared__ __bf16 shB[32 * 264];           // [t][k], row 256+8 pad (16.5 KB)
    __shared__ float hsqp[8][32];              // partial ||h_t||^2 by k-octant
    __shared__ float mrg_m[4][2][16], mrg_l[4][2][16];

    int bn = blockIdx.x;
    int t0 = blockIdx.y * 32;
    int sc = blockIdx.z;
    int tid = threadIdx.x;
    int lane = tid & 63;
    int n = lane & 15;          // A-row / B-col / C-col lane field
    int q = lane >> 4;          // quad
    int w = tid >> 6;           // wave

    // ---- stage H tile -> LDS bf16 [t][k]; fp32 hsq partials on the side ----
    const float* Hb = H + (size_t)bn * Dd * Tt;
    unsigned* shU = (unsigned*)shB;
    float hacc = 0.f;
    int tt = tid & 31;          // this thread's t-within-tile (constant)
    int kg = tid >> 5;          // k-group 0..7
    int t = t0 + tt;
    bool tok = (t < Tt);
    #pragma unroll 4
    for (int p = 0; p < 16; ++p) {
        int kp = p * 8 + kg;          // k-pair 0..127
        float v0 = 0.f, v1 = 0.f;
        if (tok) {
            v0 = Hb[(size_t)(2 * kp) * Tt + t];
            v1 = Hb[(size_t)(2 * kp + 1) * Tt + t];
        }
        hacc = fmaf(v0, v0, hacc);
        hacc = fmaf(v1, v1, hacc);
        shU[tt * 132 + kp] = pack_bf16x2(v0, v1);
    }
    hsqp[kg][tt] = hacc;
    __syncthreads();

    // ---- B fragments (2 t-subtiles, shared by all waves) ----
    v8bf bq[2][8];
    #pragma unroll
    for (int i = 0; i < 2; ++i) {
        int tloc = 16 * i + n;
        #pragma unroll
        for (int ks = 0; ks < 8; ++ks) {
            bq[i][ks] = *reinterpret_cast<const v8bf*>(&shB[tloc * 264 + ks * 32 + q * 8]);
        }
    }

    float A = alpha[0], Bv = beta[0];
    float ta2p = 2.f * A * L2E;
    float ctc2[2];
    #pragma unroll
    for (int i = 0; i < 2; ++i) {
        int tl2 = 16 * i + n;
        float hs = 0.f;
        #pragma unroll
        for (int g = 0; g < 8; ++g) hs += hsqp[g][tl2];
        ctc2[i] = (t0 + tl2 < Tt) ? ((Bv - A * hs) * L2E) : 0.f;
    }

    const __bf16* ebf = (const __bf16*)((const char*)ws + EBF_BYTES);
    float lm[2], ll[2];
    #pragma unroll
    for (int i = 0; i < 2; ++i) { lm[i] = -INFINITY; ll[i] = 0.f; }

    for (int step = 0; step < 8; ++step) {
        int sb = sc * 512 + step * 64 + w * 16;   // this wave's 16-speaker base
        const v8bf* ap = (const v8bf*)(ebf + (size_t)(sb + n) * Dd + q * 8);
        v8bf af[8];
        #pragma unroll
        for (int ks = 0; ks < 8; ++ks) af[ks] = ap[ks * 4];  // stride 32 bf16
        v4f acc[2];
        #pragma unroll
        for (int i = 0; i < 2; ++i) acc[i] = (v4f){0.f, 0.f, 0.f, 0.f};
        #pragma unroll
        for (int ks = 0; ks < 8; ++ks) {
            #pragma unroll
            for (int i = 0; i < 2; ++i) {
                acc[i] = __builtin_amdgcn_mfma_f32_16x16x32_bf16(af[ks], bq[i][ks], acc[i], 0, 0, 0);
            }
        }
        // epilogue (log2 domain, branchless): v2 = ctc2 + esn2 + ta2p*dot
        float4 es4 = *(const float4*)(ws + F_ESN + sb + q * 4);
        float esr[4] = {es4.x, es4.y, es4.z, es4.w};
        #pragma unroll
        for (int i = 0; i < 2; ++i) {
            #pragma unroll
            for (int r = 0; r < 4; ++r) {
                float v = fmaf(ta2p, acc[i][r], ctc2[i] + esr[r]);
                float nm = fmaxf(lm[i], v);
                ll[i] = ll[i] * EXP2F(lm[i] - nm) + EXP2F(v - nm);
                lm[i] = nm;
            }
        }
    }

    // ---- merge quads within wave ----
    #pragma unroll
    for (int i = 0; i < 2; ++i) {
        float m = lm[i], l = ll[i];
        #pragma unroll
        for (int msk = 16; msk <= 32; msk <<= 1) {
            float om = __shfl_xor(m, msk, 64);
            float ol = __shfl_xor(l, msk, 64);
            float nm = fmaxf(m, om);
            l = l * EXP2F(m - nm) + ol * EXP2F(om - nm);
            m = nm;
        }
        if (q == 0) { mrg_m[w][i][n] = m; mrg_l[w][i][n] = l; }
    }
    __syncthreads();

    // ---- merge waves (different speakers, same t), write partials ----
    if (tid < 32) {
        int i = tid >> 4, c = tid & 15;
        float m = mrg_m[0][i][c], l = mrg_l[0][i][c];
        #pragma unroll
        for (int wv = 1; wv < 4; ++wv) {
            float om = mrg_m[wv][i][c], ol = mrg_l[wv][i][c];
            float nm = fmaxf(m, om);
            l = l * EXP2F(m - nm) + ol * EXP2F(om - nm);
            m = nm;
        }
        int tw = t0 + 16 * i + c;
        if (tw < Tt) {
            ws[F_PM + (bn * 512 + tw) * 4 + sc] = m;
            ws[F_PL + (bn * 512 + tw) * 4 + sc] = l;
        }
    }
}

// ================= kernel 3: final combine (1024 threads) =================
__global__ __launch_bounds__(1024) void final_kernel(const float* __restrict__ ws,
                                                     float* __restrict__ out) {
    __shared__ float rL[16], rD[16];
    int tid = threadIdx.x;
    float lsum = 0.f;
    #pragma unroll
    for (int it = 0; it < 8; ++it) {
        int idx = it * 1024 + tid;     // 0..8191
        int bn = idx >> 9, t = idx & 511;
        if (t < Tt) {
            int base = (bn * 512 + t) * 4;
            float m = ws[F_PM + base], l = ws[F_PL + base];
            #pragma unroll
            for (int s = 1; s < 4; ++s) {
                float om = ws[F_PM + base + s], ol = ws[F_PL + base + s];
                float nm = fmaxf(m, om);
                l = l * EXP2F(m - nm) + ol * EXP2F(om - nm);
                m = nm;
            }
            lsum += LN2 * (m + LOG2F(l));   // back to natural log
        }
    }
    float dsum = (tid < 64) ? ws[F_DMINP + tid] : 0.f;
    #pragma unroll
    for (int off = 32; off > 0; off >>= 1) {
        lsum += __shfl_down(lsum, off, 64);
        dsum += __shfl_down(dsum, off, 64);
    }
    if ((tid & 63) == 0) { rL[tid >> 6] = lsum; rD[tid >> 6] = dsum; }
    __syncthreads();
    if (tid == 0) {
        float L = 0.f, D = 0.f;
        #pragma unroll
        for (int wv = 0; wv < 16; ++wv) { L += rL[wv]; D += rD[wv]; }
        out[BN * Dd] = -(D / (float)(Bb * Tt)) + L / (float)(BN * Tt);
    }
}

extern "C" void kernel_launch(void* const* d_in, const int* in_sizes, int n_in,
                              void* d_out, int out_size, void* d_ws, size_t ws_size,
                              hipStream_t stream) {
    const float* H     = (const float*)d_in[0];
    const int*   S     = (const int*)d_in[1];
    const float* E     = (const float*)d_in[2];
    const float* alpha = (const float*)d_in[3];
    const float* beta  = (const float*)d_in[4];
    float* out = (float*)d_out;
    float* ws  = (float*)d_ws;

    prep_all_kernel<<<592, 256, 0, stream>>>(E, S, H, alpha, beta, ws, out);
    lse_mfma_kernel<<<dim3(BN, 16, 4), 256, 0, stream>>>(H, alpha, beta, ws);
    final_kernel<<<1, 1024, 0, stream>>>(ws, out);
}

// Round 6
// 135.354 us; speedup vs baseline: 1.0570x; 1.0570x over previous
//
#include <hip/hip_runtime.h>
#include <math.h>

// Problem constants
#define Bb   8
#define Dd   256
#define Tt   500
#define SPK  2000
#define SPKP 2048     // padded speakers
#define BN   16       // B*N
#define L2E  1.4426950408889634f
#define LN2  0.6931471805599453f

// fast hw transcendentals: v_exp_f32 = 2^x, v_log_f32 = log2(x)
#define EXP2F(x) __builtin_amdgcn_exp2f(x)
#define LOG2F(x) __builtin_amdgcn_logf(x)

// ---- ws layout (float indices) ----
#define F_ESN   0                      // -alpha*||E_s||^2 * log2(e), pad rows = -1e30   [2048]
#define F_DMINP 2048                   // per-block dmin partial sums          [128]
#define F_PM    4096                   // partial m (log2 domain) [16*512*4]
#define F_PL    (F_PM + 32768)         // partial l [16*512*4]
#define EBF_FLOATS (F_PL + 32768)      // = 69632
#define EBF_BYTES ((size_t)EBF_FLOATS * 4)

typedef __bf16 v8bf __attribute__((ext_vector_type(8)));
typedef float  v4f  __attribute__((ext_vector_type(4)));

__device__ inline unsigned pack_bf16x2(float lo, float hi) {
    union { __bf16 h; unsigned short u; } a, b;
    a.h = (__bf16)lo; b.h = (__bf16)hi;
    return ((unsigned)b.u << 16) | (unsigned)a.u;
}

// ================= kernel 1: prep_all =================
// blocks 0..511   : E -> bf16 (4 rows/block) + esn2 (log2-scaled)
// blocks 512..527 : gather out[0..4095]
// blocks 528..655 : dmin partials (128 blocks: 8 b x 16 t-tiles of 32, 8-way d-split)
__global__ __launch_bounds__(256) void prep_all_kernel(
        const float* __restrict__ E, const int* __restrict__ S,
        const float* __restrict__ H, const float* __restrict__ alpha,
        const float* __restrict__ beta, float* __restrict__ ws,
        float* __restrict__ out) {
    int bid = blockIdx.x;
    int tid = threadIdx.x;

    if (bid < 512) {
        int s = bid * 4 + (tid >> 6);     // 0..2047
        int lane = tid & 63;
        float4 v = make_float4(0.f, 0.f, 0.f, 0.f);
        if (s < SPK) v = ((const float4*)E)[s * 64 + lane];
        __bf16* ebf = (__bf16*)((char*)ws + EBF_BYTES);
        uint2 pp;
        pp.x = pack_bf16x2(v.x, v.y);
        pp.y = pack_bf16x2(v.z, v.w);
        *(uint2*)(ebf + (size_t)s * Dd + lane * 4) = pp;
        float acc = v.x * v.x + v.y * v.y + v.z * v.z + v.w * v.w;
        #pragma unroll
        for (int off = 32; off > 0; off >>= 1) acc += __shfl_down(acc, off, 64);
        if (lane == 0) ws[F_ESN + s] = (s < SPK) ? (-alpha[0] * acc * L2E) : -1e30f;
    } else if (bid < 528) {
        int i = (bid - 512) * 256 + tid;  // 0..4095
        int bn = i >> 8, d = i & 255;
        out[i] = E[(size_t)S[bn * Tt] * Dd + d];
    } else {
        __shared__ float4 shm[8][32];
        int qq = bid - 528;               // 0..127
        int b = qq >> 4;
        int t0 = (qq & 15) * 32;
        int tl = tid & 31;
        int wv = tid >> 5;                // 0..7, d-split
        int t = t0 + tl;
        bool ok = (t < Tt);
        int tc = ok ? t : (Tt - 1);
        int s0 = S[(b * 2 + 0) * Tt + tc];
        int s1 = S[(b * 2 + 1) * Tt + tc];
        const float* h0 = H + ((size_t)(b * 2 + 0) * Dd) * Tt + tc;
        const float* h1 = H + ((size_t)(b * 2 + 1) * Dd) * Tt + tc;
        const float* e0 = E + (size_t)s0 * Dd;
        const float* e1 = E + (size_t)s1 * Dd;
        float d00 = 0, d01 = 0, d10 = 0, d11 = 0;
        int dbase = wv * 32;
        #pragma unroll 4
        for (int dd = 0; dd < 32; ++dd) {
            int d = dbase + dd;
            float x0 = h0[(size_t)d * Tt], x1 = h1[(size_t)d * Tt];
            float y0 = e0[d], y1 = e1[d];
            float u;
            u = x0 - y0; d00 = fmaf(u, u, d00);
            u = x0 - y1; d01 = fmaf(u, u, d01);
            u = x1 - y0; d10 = fmaf(u, u, d10);
            u = x1 - y1; d11 = fmaf(u, u, d11);
        }
        shm[wv][tl] = make_float4(d00, d01, d10, d11);
        __syncthreads();
        if (tid < 32) {
            d00 = 0; d01 = 0; d10 = 0; d11 = 0;
            #pragma unroll
            for (int g = 0; g < 8; ++g) {
                float4 p = shm[g][tl];
                d00 += p.x; d01 += p.y; d10 += p.z; d11 += p.w;
            }
            float dm = fminf(d00 + d11, d01 + d10);
            float val = ok ? (-alpha[0] * dm + beta[0]) : 0.f;
            #pragma unroll
            for (int off = 16; off > 0; off >>= 1) val += __shfl_down(val, off, 32);
            if (tid == 0) ws[F_DMINP + qq] = val;
        }
    }
}

// ================= kernel 2: MFMA lse (log2 domain, pipelined) =================
// grid (bn=16, ttile=16 [32 t], schunk=4 [512 spk]), 256 threads = 4 waves (speaker-split)
__global__ __launch_bounds__(256, 2) void lse_mfma_kernel(
        const float* __restrict__ H, const float* __restrict__ alpha,
        const float* __restrict__ beta, float* __restrict__ ws) {
    __shared__ __bf16 shB[32 * 264];           // [t][k], row 256+8 pad (16.5 KB)
    __shared__ float hsqp[8][32];              // partial ||h_t||^2 by k-octant
    __shared__ float mrg_m[4][2][16], mrg_l[4][2][16];

    int bn = blockIdx.x;
    int t0 = blockIdx.y * 32;
    int sc = blockIdx.z;
    int tid = threadIdx.x;
    int lane = tid & 63;
    int n = lane & 15;          // A-row (speaker) / C-col lane field
    int q = lane >> 4;          // quad
    int w = tid >> 6;           // wave

    const __bf16* ebf = (const __bf16*)((const char*)ws + EBF_BYTES);
    int sb0 = sc * 512 + w * 16;               // this wave's speaker base

    // ---- issue first A-fragment + esn loads early (hidden behind staging) ----
    v8bf af[2][8];
    float4 es[2];
    {
        const v8bf* ap = (const v8bf*)(ebf + (size_t)(sb0 + n) * Dd + q * 8);
        #pragma unroll
        for (int ks = 0; ks < 8; ++ks) af[0][ks] = ap[ks * 4];
        es[0] = *(const float4*)(ws + F_ESN + sb0 + q * 4);
    }

    // ---- stage H tile -> LDS bf16 [t][k]; fp32 hsq partials on the side ----
    const float* Hb = H + (size_t)bn * Dd * Tt;
    unsigned* shU = (unsigned*)shB;
    float hacc = 0.f;
    int tt = tid & 31;          // this thread's t-within-tile
    int kg = tid >> 5;          // k-group 0..7
    int t = t0 + tt;
    bool tok = (t < Tt);
    #pragma unroll 4
    for (int p = 0; p < 16; ++p) {
        int kp = p * 8 + kg;          // k-pair 0..127
        float v0 = 0.f, v1 = 0.f;
        if (tok) {
            v0 = Hb[(size_t)(2 * kp) * Tt + t];
            v1 = Hb[(size_t)(2 * kp + 1) * Tt + t];
        }
        hacc = fmaf(v0, v0, hacc);
        hacc = fmaf(v1, v1, hacc);
        shU[tt * 132 + kp] = pack_bf16x2(v0, v1);
    }
    hsqp[kg][tt] = hacc;
    __syncthreads();

    // ---- B fragments (2 t-subtiles, shared by all waves) ----
    v8bf bq[2][8];
    #pragma unroll
    for (int i = 0; i < 2; ++i) {
        int tloc = 16 * i + n;
        #pragma unroll
        for (int ks = 0; ks < 8; ++ks) {
            bq[i][ks] = *reinterpret_cast<const v8bf*>(&shB[tloc * 264 + ks * 32 + q * 8]);
        }
    }

    float A = alpha[0], Bv = beta[0];
    float ta2p = 2.f * A * L2E;
    float ctc2[2];
    #pragma unroll
    for (int i = 0; i < 2; ++i) {
        int tl2 = 16 * i + n;
        float hs = 0.f;
        #pragma unroll
        for (int g = 0; g < 8; ++g) hs += hsqp[g][tl2];
        ctc2[i] = (t0 + tl2 < Tt) ? ((Bv - A * hs) * L2E) : 0.f;
    }

    float lm[2], ll[2];
    #pragma unroll
    for (int i = 0; i < 2; ++i) { lm[i] = -INFINITY; ll[i] = 0.f; }

    #pragma unroll
    for (int step = 0; step < 8; ++step) {
        int cb = step & 1, nb = cb ^ 1;
        // ---- prefetch next step's A-fragments + esn ----
        if (step < 7) {
            int sbn = sb0 + (step + 1) * 64;
            const v8bf* ap = (const v8bf*)(ebf + (size_t)(sbn + n) * Dd + q * 8);
            #pragma unroll
            for (int ks = 0; ks < 8; ++ks) af[nb][ks] = ap[ks * 4];
            es[nb] = *(const float4*)(ws + F_ESN + sbn + q * 4);
        }
        // ---- 16 MFMAs on current buffer ----
        v4f acc[2];
        #pragma unroll
        for (int i = 0; i < 2; ++i) acc[i] = (v4f){0.f, 0.f, 0.f, 0.f};
        #pragma unroll
        for (int ks = 0; ks < 8; ++ks) {
            #pragma unroll
            for (int i = 0; i < 2; ++i) {
                acc[i] = __builtin_amdgcn_mfma_f32_16x16x32_bf16(af[cb][ks], bq[i][ks], acc[i], 0, 0, 0);
            }
        }
        // ---- tree epilogue (log2 domain): parallel exps, one merge ----
        float e0 = es[cb].x, e1 = es[cb].y, e2 = es[cb].z, e3 = es[cb].w;
        #pragma unroll
        for (int i = 0; i < 2; ++i) {
            float v0 = fmaf(ta2p, acc[i][0], ctc2[i] + e0);
            float v1 = fmaf(ta2p, acc[i][1], ctc2[i] + e1);
            float v2 = fmaf(ta2p, acc[i][2], ctc2[i] + e2);
            float v3 = fmaf(ta2p, acc[i][3], ctc2[i] + e3);
            float vm = fmaxf(fmaxf(v0, v1), fmaxf(v2, v3));
            float s = EXP2F(v0 - vm) + EXP2F(v1 - vm) + EXP2F(v2 - vm) + EXP2F(v3 - vm);
            float nm = fmaxf(lm[i], vm);
            ll[i] = ll[i] * EXP2F(lm[i] - nm) + s * EXP2F(vm - nm);
            lm[i] = nm;
        }
    }

    // ---- merge quads within wave ----
    #pragma unroll
    for (int i = 0; i < 2; ++i) {
        float m = lm[i], l = ll[i];
        #pragma unroll
        for (int msk = 16; msk <= 32; msk <<= 1) {
            float om = __shfl_xor(m, msk, 64);
            float ol = __shfl_xor(l, msk, 64);
            float nm = fmaxf(m, om);
            l = l * EXP2F(m - nm) + ol * EXP2F(om - nm);
            m = nm;
        }
        if (q == 0) { mrg_m[w][i][n] = m; mrg_l[w][i][n] = l; }
    }
    __syncthreads();

    // ---- merge waves (different speakers, same t), write partials ----
    if (tid < 32) {
        int i = tid >> 4, c = tid & 15;
        float m = mrg_m[0][i][c], l = mrg_l[0][i][c];
        #pragma unroll
        for (int wv = 1; wv < 4; ++wv) {
            float om = mrg_m[wv][i][c], ol = mrg_l[wv][i][c];
            float nm = fmaxf(m, om);
            l = l * EXP2F(m - nm) + ol * EXP2F(om - nm);
            m = nm;
        }
        int tw = t0 + 16 * i + c;
        if (tw < Tt) {
            ws[F_PM + (bn * 512 + tw) * 4 + sc] = m;
            ws[F_PL + (bn * 512 + tw) * 4 + sc] = l;
        }
    }
}

// ================= kernel 3: final combine (1024 threads) =================
__global__ __launch_bounds__(1024) void final_kernel(const float* __restrict__ ws,
                                                     float* __restrict__ out) {
    __shared__ float rL[16], rD[16];
    int tid = threadIdx.x;
    float lsum = 0.f;
    #pragma unroll
    for (int it = 0; it < 8; ++it) {
        int idx = it * 1024 + tid;     // 0..8191
        int bn = idx >> 9, t = idx & 511;
        if (t < Tt) {
            int base = (bn * 512 + t) * 4;
            float m = ws[F_PM + base], l = ws[F_PL + base];
            #pragma unroll
            for (int s = 1; s < 4; ++s) {
                float om = ws[F_PM + base + s], ol = ws[F_PL + base + s];
                float nm = fmaxf(m, om);
                l = l * EXP2F(m - nm) + ol * EXP2F(om - nm);
                m = nm;
            }
            lsum += LN2 * (m + LOG2F(l));   // back to natural log
        }
    }
    float dsum = (tid < 128) ? ws[F_DMINP + tid] : 0.f;
    #pragma unroll
    for (int off = 32; off > 0; off >>= 1) {
        lsum += __shfl_down(lsum, off, 64);
        dsum += __shfl_down(dsum, off, 64);
    }
    if ((tid & 63) == 0) { rL[tid >> 6] = lsum; rD[tid >> 6] = dsum; }
    __syncthreads();
    if (tid == 0) {
        float L = 0.f, D = 0.f;
        #pragma unroll
        for (int wv = 0; wv < 16; ++wv) { L += rL[wv]; D += rD[wv]; }
        out[BN * Dd] = -(D / (float)(Bb * Tt)) + L / (float)(BN * Tt);
    }
}

extern "C" void kernel_launch(void* const* d_in, const int* in_sizes, int n_in,
                              void* d_out, int out_size, void* d_ws, size_t ws_size,
                              hipStream_t stream) {
    const float* H     = (const float*)d_in[0];
    const int*   S     = (const int*)d_in[1];
    const float* E     = (const float*)d_in[2];
    const float* alpha = (const float*)d_in[3];
    const float* beta  = (const float*)d_in[4];
    float* out = (float*)d_out;
    float* ws  = (float*)d_ws;

    prep_all_kernel<<<656, 256, 0, stream>>>(E, S, H, alpha, beta, ws, out);
    lse_mfma_kernel<<<dim3(BN, 16, 4), 256, 0, stream>>>(H, alpha, beta, ws);
    final_kernel<<<1, 1024, 0, stream>>>(ws, out);
}

// Round 7
// 100.649 us; speedup vs baseline: 1.4215x; 1.3448x over previous
//
#include <hip/hip_runtime.h>
#include <math.h>

// Problem constants
#define Bb   8
#define Dd   256
#define Tt   500
#define SPK  2000
#define SPKP 2048
#define BN   16       // B*N
#define L2E  1.4426950408889634f
#define LN2  0.6931471805599453f

#define EXP2F(x) __builtin_amdgcn_exp2f(x)
#define LOG2F(x) __builtin_amdgcn_logf(x)

// ---- ws layout ----
#define F_ESN   0                      // -alpha*||E_s||^2*log2e, pad=-1e30  [2048]
#define F_DMINP 2048                   // dmin partials [128]
#define F_HSQP  4096                   // hsq partials [16][512][4]
#define F_PM    36864                  // partial m (log2 dom) [16*512*4]
#define F_PL    69632                  // partial l [16*512*4]
#define EBF_BYTES ((size_t)102400 * 4)            // 409600: bf16 E [2048][256]
#define HBF_BYTES (EBF_BYTES + (size_t)1048576)   // bf16 H^T [16][512][256]

typedef __bf16 v8bf __attribute__((ext_vector_type(8)));
typedef float  v4f  __attribute__((ext_vector_type(4)));

__device__ inline unsigned pack_bf16x2(float lo, float hi) {
    union { __bf16 h; unsigned short u; } a, b;
    a.h = (__bf16)lo; b.h = (__bf16)hi;
    return ((unsigned)b.u << 16) | (unsigned)a.u;
}

// ================= kernel 1: prep_all =================
// blocks 0..511    : E -> bf16 + esn
// blocks 512..527  : gather out
// blocks 528..655  : dmin partials
// blocks 656..1679 : H transpose -> hbf bf16 [bn][t][k] + hsq partials
__global__ __launch_bounds__(256) void prep_all_kernel(
        const float* __restrict__ E, const int* __restrict__ S,
        const float* __restrict__ H, const float* __restrict__ alpha,
        const float* __restrict__ beta, float* __restrict__ ws,
        float* __restrict__ out) {
    int bid = blockIdx.x;
    int tid = threadIdx.x;

    if (bid < 512) {
        int s = bid * 4 + (tid >> 6);
        int lane = tid & 63;
        float4 v = make_float4(0.f, 0.f, 0.f, 0.f);
        if (s < SPK) v = ((const float4*)E)[s * 64 + lane];
        __bf16* ebf = (__bf16*)((char*)ws + EBF_BYTES);
        uint2 pp;
        pp.x = pack_bf16x2(v.x, v.y);
        pp.y = pack_bf16x2(v.z, v.w);
        *(uint2*)(ebf + (size_t)s * Dd + lane * 4) = pp;
        float acc = v.x * v.x + v.y * v.y + v.z * v.z + v.w * v.w;
        #pragma unroll
        for (int off = 32; off > 0; off >>= 1) acc += __shfl_down(acc, off, 64);
        if (lane == 0) ws[F_ESN + s] = (s < SPK) ? (-alpha[0] * acc * L2E) : -1e30f;
    } else if (bid < 528) {
        int i = (bid - 512) * 256 + tid;
        int bn = i >> 8, d = i & 255;
        out[i] = E[(size_t)S[bn * Tt] * Dd + d];
    } else if (bid < 656) {
        __shared__ float4 shm[8][32];
        int qq = bid - 528;               // 0..127
        int b = qq >> 4;
        int t0 = (qq & 15) * 32;
        int tl = tid & 31;
        int wv = tid >> 5;
        int t = t0 + tl;
        bool ok = (t < Tt);
        int tc = ok ? t : (Tt - 1);
        int s0 = S[(b * 2 + 0) * Tt + tc];
        int s1 = S[(b * 2 + 1) * Tt + tc];
        const float* h0 = H + ((size_t)(b * 2 + 0) * Dd) * Tt + tc;
        const float* h1 = H + ((size_t)(b * 2 + 1) * Dd) * Tt + tc;
        const float* e0 = E + (size_t)s0 * Dd;
        const float* e1 = E + (size_t)s1 * Dd;
        float d00 = 0, d01 = 0, d10 = 0, d11 = 0;
        int dbase = wv * 32;
        #pragma unroll 4
        for (int dd = 0; dd < 32; ++dd) {
            int d = dbase + dd;
            float x0 = h0[(size_t)d * Tt], x1 = h1[(size_t)d * Tt];
            float y0 = e0[d], y1 = e1[d];
            float u;
            u = x0 - y0; d00 = fmaf(u, u, d00);
            u = x0 - y1; d01 = fmaf(u, u, d01);
            u = x1 - y0; d10 = fmaf(u, u, d10);
            u = x1 - y1; d11 = fmaf(u, u, d11);
        }
        shm[wv][tl] = make_float4(d00, d01, d10, d11);
        __syncthreads();
        if (tid < 32) {
            d00 = 0; d01 = 0; d10 = 0; d11 = 0;
            #pragma unroll
            for (int g = 0; g < 8; ++g) {
                float4 p = shm[g][tl];
                d00 += p.x; d01 += p.y; d10 += p.z; d11 += p.w;
            }
            float dm = fminf(d00 + d11, d01 + d10);
            float val = ok ? (-alpha[0] * dm + beta[0]) : 0.f;
            #pragma unroll
            for (int off = 16; off > 0; off >>= 1) val += __shfl_down(val, off, 32);
            if (tid == 0) ws[F_DMINP + qq] = val;
        }
    } else {
        // ---- H transpose tile: (bn, 32 t) x (64 d) ----
        __shared__ float trans[32][65];
        int u = bid - 656;                 // 0..1023
        int bn = u >> 6;
        int r = u & 63;
        int tt0 = (r & 15) * 32;
        int d0 = (r >> 4) * 64;
        const float* Hb = H + (size_t)bn * Dd * Tt;
        #pragma unroll
        for (int p = 0; p < 8; ++p) {
            int flat = p * 256 + tid;      // 0..2047
            int dd = flat >> 5;            // 0..63
            int tl = flat & 31;
            int t = tt0 + tl;
            trans[tl][dd] = (t < Tt) ? Hb[(size_t)(d0 + dd) * Tt + t] : 0.f;
        }
        __syncthreads();
        int tw = tid >> 3;                 // 0..31
        int j = tid & 7;
        float sq = 0.f;
        float vals[8];
        #pragma unroll
        for (int e = 0; e < 8; ++e) {
            float x = trans[tw][j * 8 + e];
            vals[e] = x;
            sq = fmaf(x, x, sq);
        }
        sq += __shfl_xor(sq, 1, 64);
        sq += __shfl_xor(sq, 2, 64);
        sq += __shfl_xor(sq, 4, 64);
        uint4 pk;
        pk.x = pack_bf16x2(vals[0], vals[1]);
        pk.y = pack_bf16x2(vals[2], vals[3]);
        pk.z = pack_bf16x2(vals[4], vals[5]);
        pk.w = pack_bf16x2(vals[6], vals[7]);
        __bf16* hbf = (__bf16*)((char*)ws + HBF_BYTES);
        *(uint4*)(hbf + ((size_t)(bn * 512 + tt0 + tw) * Dd + d0 + j * 8)) = pk;
        if (j == 0) ws[F_HSQP + (size_t)(bn * 512 + tt0 + tw) * 4 + (r >> 4)] = sq;
    }
}

// ================= kernel 2: MFMA lse v3 (LDS-staged GEMM) =================
// grid (bn=16, ttile=8 [64 t], mz=4 [512 spk]); 256 thr = 4 waves (spk-split in chunk)
__global__ __launch_bounds__(256, 2) void lse_mfma_kernel(
        const float* __restrict__ alpha, const float* __restrict__ beta,
        float* __restrict__ ws) {
    __shared__ __bf16 shB[64 * 264];           // H^T tile [t][k], stride 264
    __shared__ __bf16 shA[64 * 264];           // E chunk [spk][k], stride 264
    __shared__ float mrg_m[4][4][16], mrg_l[4][4][16];

    int bn = blockIdx.x;
    int t0 = blockIdx.y * 64;
    int mz = blockIdx.z;
    int tid = threadIdx.x;
    int lane = tid & 63;
    int n = lane & 15;
    int q = lane >> 4;
    int w = tid >> 6;

    const __bf16* ebf = (const __bf16*)((const char*)ws + EBF_BYTES);
    const __bf16* hbf = (const __bf16*)((const char*)ws + HBF_BYTES);

    // ---- stage B tile (64 t x 256 k): coalesced uint4 -> LDS ----
    #pragma unroll
    for (int p = 0; p < 8; ++p) {
        int flat = p * 256 + tid;          // 0..2047
        int row = flat >> 5;               // 0..63
        int ch = flat & 31;                // 16-B chunk
        uint4 v = *(const uint4*)(hbf + ((size_t)(bn * 512 + t0 + row) * Dd + ch * 8));
        *(uint4*)(shB + row * 264 + ch * 8) = v;
    }
    __syncthreads();

    // ---- B fragments: all 4 t-subtiles in registers ----
    v8bf bq[4][8];
    #pragma unroll
    for (int i = 0; i < 4; ++i) {
        int tloc = 16 * i + n;
        #pragma unroll
        for (int ks = 0; ks < 8; ++ks) {
            bq[i][ks] = *reinterpret_cast<const v8bf*>(&shB[tloc * 264 + ks * 32 + q * 8]);
        }
    }

    float A = alpha[0], Bv = beta[0];
    float ta2p = 2.f * A * L2E;
    float ctc2[4];
    #pragma unroll
    for (int i = 0; i < 4; ++i) {
        int t = t0 + 16 * i + n;
        float4 hq = *(const float4*)(ws + F_HSQP + (size_t)(bn * 512 + t) * 4);
        float hs = hq.x + hq.y + hq.z + hq.w;
        ctc2[i] = (t < Tt) ? ((Bv - A * hs) * L2E) : 0.f;
    }

    float lm[4], ll[4];
    #pragma unroll
    for (int i = 0; i < 4; ++i) { lm[i] = -INFINITY; ll[i] = 0.f; }

    for (int c = 0; c < 8; ++c) {
        int sbase = mz * 512 + c * 64;
        __syncthreads();   // protect shA from previous chunk's readers
        #pragma unroll
        for (int p = 0; p < 8; ++p) {
            int flat = p * 256 + tid;
            int row = flat >> 5;
            int ch = flat & 31;
            uint4 v = *(const uint4*)(ebf + ((size_t)(sbase + row) * Dd + ch * 8));
            *(uint4*)(shA + row * 264 + ch * 8) = v;
        }
        __syncthreads();

        // this wave's 16-speaker m-frag
        int sb = sbase + w * 16;
        v8bf af[8];
        #pragma unroll
        for (int ks = 0; ks < 8; ++ks) {
            af[ks] = *reinterpret_cast<const v8bf*>(&shA[(w * 16 + n) * 264 + ks * 32 + q * 8]);
        }
        float4 es4 = *(const float4*)(ws + F_ESN + sb + q * 4);

        v4f acc[4];
        #pragma unroll
        for (int i = 0; i < 4; ++i) acc[i] = (v4f){0.f, 0.f, 0.f, 0.f};
        #pragma unroll
        for (int ks = 0; ks < 8; ++ks) {
            #pragma unroll
            for (int i = 0; i < 4; ++i) {
                acc[i] = __builtin_amdgcn_mfma_f32_16x16x32_bf16(af[ks], bq[i][ks], acc[i], 0, 0, 0);
            }
        }
        float e0 = es4.x, e1 = es4.y, e2 = es4.z, e3 = es4.w;
        #pragma unroll
        for (int i = 0; i < 4; ++i) {
            float c2 = ctc2[i];
            float v0 = fmaf(ta2p, acc[i][0], c2 + e0);
            float v1 = fmaf(ta2p, acc[i][1], c2 + e1);
            float v2 = fmaf(ta2p, acc[i][2], c2 + e2);
            float v3 = fmaf(ta2p, acc[i][3], c2 + e3);
            float vm = fmaxf(fmaxf(v0, v1), fmaxf(v2, v3));
            float s = EXP2F(v0 - vm) + EXP2F(v1 - vm) + EXP2F(v2 - vm) + EXP2F(v3 - vm);
            float nm = fmaxf(lm[i], vm);
            ll[i] = ll[i] * EXP2F(lm[i] - nm) + s * EXP2F(vm - nm);
            lm[i] = nm;
        }
    }

    // ---- merge quads within wave (t = n repeats across q) ----
    #pragma unroll
    for (int i = 0; i < 4; ++i) {
        float m = lm[i], l = ll[i];
        #pragma unroll
        for (int msk = 16; msk <= 32; msk <<= 1) {
            float om = __shfl_xor(m, msk, 64);
            float ol = __shfl_xor(l, msk, 64);
            float nm = fmaxf(m, om);
            l = l * EXP2F(m - nm) + ol * EXP2F(om - nm);
            m = nm;
        }
        if (q == 0) { mrg_m[w][i][n] = m; mrg_l[w][i][n] = l; }
    }
    __syncthreads();

    // ---- merge waves (different speakers), write partials per (bn,t,mz) ----
    if (tid < 64) {
        int i = tid >> 4, cc = tid & 15;
        float m = mrg_m[0][i][cc], l = mrg_l[0][i][cc];
        #pragma unroll
        for (int wv = 1; wv < 4; ++wv) {
            float om = mrg_m[wv][i][cc], ol = mrg_l[wv][i][cc];
            float nm = fmaxf(m, om);
            l = l * EXP2F(m - nm) + ol * EXP2F(om - nm);
            m = nm;
        }
        int tw = t0 + 16 * i + cc;
        if (tw < Tt) {
            ws[F_PM + (bn * 512 + tw) * 4 + mz] = m;
            ws[F_PL + (bn * 512 + tw) * 4 + mz] = l;
        }
    }
}

// ================= kernel 3: final combine =================
__global__ __launch_bounds__(1024) void final_kernel(const float* __restrict__ ws,
                                                     float* __restrict__ out) {
    __shared__ float rL[16], rD[16];
    int tid = threadIdx.x;
    float lsum = 0.f;
    #pragma unroll
    for (int it = 0; it < 8; ++it) {
        int idx = it * 1024 + tid;
        int bn = idx >> 9, t = idx & 511;
        if (t < Tt) {
            int base = (bn * 512 + t) * 4;
            float m = ws[F_PM + base], l = ws[F_PL + base];
            #pragma unroll
            for (int s = 1; s < 4; ++s) {
                float om = ws[F_PM + base + s], ol = ws[F_PL + base + s];
                float nm = fmaxf(m, om);
                l = l * EXP2F(m - nm) + ol * EXP2F(om - nm);
                m = nm;
            }
            lsum += LN2 * (m + LOG2F(l));
        }
    }
    float dsum = (tid < 128) ? ws[F_DMINP + tid] : 0.f;
    #pragma unroll
    for (int off = 32; off > 0; off >>= 1) {
        lsum += __shfl_down(lsum, off, 64);
        dsum += __shfl_down(dsum, off, 64);
    }
    if ((tid & 63) == 0) { rL[tid >> 6] = lsum; rD[tid >> 6] = dsum; }
    __syncthreads();
    if (tid == 0) {
        float L = 0.f, D = 0.f;
        #pragma unroll
        for (int wv = 0; wv < 16; ++wv) { L += rL[wv]; D += rD[wv]; }
        out[BN * Dd] = -(D / (float)(Bb * Tt)) + L / (float)(BN * Tt);
    }
}

extern "C" void kernel_launch(void* const* d_in, const int* in_sizes, int n_in,
                              void* d_out, int out_size, void* d_ws, size_t ws_size,
                              hipStream_t stream) {
    const float* H     = (const float*)d_in[0];
    const int*   S     = (const int*)d_in[1];
    const float* E     = (const float*)d_in[2];
    const float* alpha = (const float*)d_in[3];
    const float* beta  = (const float*)d_in[4];
    float* out = (float*)d_out;
    float* ws  = (float*)d_ws;

    prep_all_kernel<<<1680, 256, 0, stream>>>(E, S, H, alpha, beta, ws, out);
    lse_mfma_kernel<<<dim3(BN, 8, 4), 256, 0, stream>>>(alpha, beta, ws);
    final_kernel<<<1, 1024, 0, stream>>>(ws, out);
}